// Round 12
// baseline (342.722 us; speedup 1.0000x reference)
//
#include <hip/hip_runtime.h>

#define BB 16      // batch
#define CC 64      // channels (Cin = Cout = 64)
#define HH 128
#define WW 128
#define MM 67      // modes per axis
#define MODES (MM*MM)   // 4489
#define MC 32      // mode chunk for mix
#define NCHUNK 141 // ceil(4489/32)

typedef float f4 __attribute__((ext_vector_type(4)));

__constant__ float DEC_LO[8] = {-0.010597401784997278f, 0.032883011666982945f, 0.030841381835986965f,
                                -0.18703481171888114f, -0.02798376941698385f, 0.6308807679295904f,
                                0.7148465705525415f, 0.23037781330885523f};
__constant__ float DEC_HI[8] = {-0.23037781330885523f, 0.7148465705525415f, -0.6308807679295904f,
                                -0.02798376941698385f, 0.18703481171888114f, 0.030841381835986965f,
                                -0.032883011666982945f, -0.010597401784997278f};

// ---------------- analysis along W: x (B,C,H,W) -> t1 (B,C,2,H,67) ----------------
__global__ __launch_bounds__(256) void dwt_w(const float* __restrict__ x, float* __restrict__ t1) {
    __shared__ float row[8][128];
    const int bc = blockIdx.x;           // 0..1023
    const int h0 = blockIdx.y * 8;       // 0..120
    const int t  = threadIdx.x;
    {
        int r = t >> 5, c = (t & 31) << 2;
        const float4 v = *(const float4*)&x[((size_t)bc * HH + h0 + r) * WW + c];
        row[r][c] = v.x; row[r][c+1] = v.y; row[r][c+2] = v.z; row[r][c+3] = v.w;
    }
    __syncthreads();
    for (int oidx = t; oidx < 8 * 2 * MM; oidx += 256) {
        int wo = oidx % MM;
        int f  = (oidx / MM) & 1;
        int r  = oidx / (2 * MM);
        const float* flt = f ? DEC_HI : DEC_LO;
        float acc = 0.f;
        int base = 2 * wo - 6;
        #pragma unroll
        for (int k = 0; k < 8; ++k) {
            int i = base + k;
            i = (i < 0) ? (-i - 1) : i;
            i = (i >= WW) ? (2 * WW - 1 - i) : i;
            acc += row[r][i] * flt[7 - k];
        }
        t1[(((size_t)bc * 2 + f) * HH + h0 + r) * MM + wo] = acc;
    }
}

// ---------------- analysis along H: t1 -> coeff (B,C,4,67,67), band = fw*2+fh ------
__global__ __launch_bounds__(256) void dwt_h(const float* __restrict__ t1, float* __restrict__ cf) {
    const int NH2 = (MM + 1) / 2;  // 34 ho-pairs
    int idx = blockIdx.x * 256 + threadIdx.x;
    const int N = BB * CC * 2 * NH2 * MM;
    if (idx >= N) return;
    int wo = idx % MM;
    int hp = (idx / MM) % NH2;
    int fw = (idx / (MM * NH2)) % 2;
    int bc = idx / (MM * NH2 * 2);
    const float* src = t1 + ((size_t)(bc * 2 + fw) * HH) * MM + wo;
    float rv[10];
    #pragma unroll
    for (int k = 0; k < 10; ++k) {
        int i = 4 * hp - 6 + k;
        i = (i < 0) ? (-i - 1) : i;
        i = (i >= HH) ? (2 * HH - 1 - i) : i;
        rv[k] = src[(size_t)i * MM];
    }
    float lo0 = 0.f, hi0 = 0.f, lo1 = 0.f, hi1 = 0.f;
    #pragma unroll
    for (int k = 0; k < 8; ++k) {
        lo0 += rv[k]     * DEC_LO[7 - k];
        hi0 += rv[k]     * DEC_HI[7 - k];
        lo1 += rv[k + 2] * DEC_LO[7 - k];
        hi1 += rv[k + 2] * DEC_HI[7 - k];
    }
    int ho0 = 2 * hp, ho1 = 2 * hp + 1;
    size_t b0 = (size_t)(bc * 4 + fw * 2 + 0) * MM;
    size_t b1 = (size_t)(bc * 4 + fw * 2 + 1) * MM;
    cf[(b0 + ho0) * MM + wo] = lo0;
    cf[(b1 + ho0) * MM + wo] = hi0;
    if (ho1 < MM) {
        cf[(b0 + ho1) * MM + wo] = lo1;
        cf[(b1 + ho1) * MM + wo] = hi1;
    }
}

// ---------------- per-mode channel mix ----------------
// out[b,o,band,m] = sum_i cf[b,i,band,m] * w_band[i,o,m]
// NO LDS, NO barriers. Block = (band, 32-mode chunk, o-quarter of 16),
// 256 threads = 4 waves, __launch_bounds__(256,6) => ~6 waves/SIMD of pure TLP
// (the LDS-tile variants of rounds 5-11 were all pinned at 1-2 waves/SIMD and
// 10-17% VALUBusy; hipcc also refuses to keep VMEM prefetch in VGPRs).
// Thread = 2b x 4o x 4m: per i = 4 weight f4 + 2 coeff f4 loads, 8 f4 FMAs.
// Cross-thread redundancy is absorbed by L1 (same-address broadcasts).
// Weights: HBM-unique per block (o-quarters partition o). Coeff chunk shared
// by its 4 sibling o-blocks: dispatch swizzle puts siblings 8 apart => same
// XCD, co-resident => L2 hits.
__global__ __launch_bounds__(256, 6) void mix_k(const float* __restrict__ cf,
                                                const float* __restrict__ w1,
                                                const float* __restrict__ w2,
                                                const float* __restrict__ w3,
                                                const float* __restrict__ w4,
                                                float* __restrict__ out) {
    // grid.x = 2272 = 71 dispatch-cycles x 32; cycle = 4 g-values x 8 XCD slots.
    // d -> (g, oq): XCD(d) ~ d%8 = g&7 -> all 4 oq of a g land on one XCD,
    // within 32 consecutive dispatch slots.
    const int d = blockIdx.x;
    const int cyc = d >> 5, r = d & 31;
    const int g  = cyc * 8 + (r & 7);      // 0..567 (>=564 invalid)
    const int oq = r >> 3;                 // 0..3
    if (g >= 4 * NCHUNK) return;
    const int band = g / NCHUNK;
    const int m0   = min((g % NCHUNK) * MC, MODES - MC);  // tail chunk overlaps (identical values)
    const int o0   = oq * 16;

    const float* w = (band == 0) ? w1 : (band == 1) ? w2 : (band == 2) ? w3 : w4;
    const int tid = threadIdx.x;
    const int m4 = tid & 7;            // mode quad: 4 floats
    const int og = (tid >> 3) & 3;     // 4 consecutive o
    const int bg = tid >> 5;           // 2 consecutive b
    const int o_t = o0 + og * 4;
    const int b_t = bg * 2;

    const size_t IST = (size_t)CC * MODES;       // weight i-stride
    const size_t CBS = (size_t)CC * 4 * MODES;   // coeff b-stride
    const float* wp = w  + (size_t)o_t * MODES + m0 + m4 * 4;                 // += IST per i
    const float* cp = cf + ((size_t)(b_t * CC) * 4 + band) * MODES + m0 + m4 * 4;  // += 4*MODES per i

    f4 acc[2][4];   // [b][o]
    #pragma unroll
    for (int j = 0; j < 2; ++j)
        #pragma unroll
        for (int k = 0; k < 4; ++k) acc[j][k] = (f4)(0.f);

    #pragma unroll 2
    for (int i = 0; i < CC; ++i) {
        f4 wv0 = *(const f4*)(wp + 0 * MODES);
        f4 wv1 = *(const f4*)(wp + 1 * MODES);
        f4 wv2 = *(const f4*)(wp + 2 * MODES);
        f4 wv3 = *(const f4*)(wp + 3 * MODES);
        f4 s0  = *(const f4*)(cp);
        f4 s1  = *(const f4*)(cp + CBS);
        acc[0][0] += s0 * wv0;  acc[0][1] += s0 * wv1;  acc[0][2] += s0 * wv2;  acc[0][3] += s0 * wv3;
        acc[1][0] += s1 * wv0;  acc[1][1] += s1 * wv1;  acc[1][2] += s1 * wv2;  acc[1][3] += s1 * wv3;
        wp += IST;
        cp += (size_t)4 * MODES;
    }

    #pragma unroll
    for (int j = 0; j < 2; ++j)
        #pragma unroll
        for (int k = 0; k < 4; ++k)
            *(f4*)&out[((size_t)(((b_t + j) * CC + o_t + k) * 4) + band) * MODES + m0 + m4 * 4] = acc[j][k];
}

// ---------------- synthesis along H: mixed (B,C,4,67,67) -> u1 (B,C,2,128,67) ------
__global__ __launch_bounds__(256) void idwt_h(const float* __restrict__ mx, float* __restrict__ u1) {
    int idx = blockIdx.x * 256 + threadIdx.x;
    const int N = BB * CC * 2 * (HH / 2) * MM;
    if (idx >= N) return;
    int wo = idx % MM;
    int a  = (idx / MM) % (HH / 2);
    int fw = (idx / (MM * (HH / 2))) % 2;
    int bc = idx / (MM * (HH / 2) * 2);
    const float* lo = mx + ((size_t)(bc * 4 + fw * 2) * MODES) + wo;
    const float* hi = lo + MODES;
    float l[4], h4[4];
    #pragma unroll
    for (int q = 0; q < 4; ++q) {
        l[q]  = lo[(size_t)(a + q) * MM];
        h4[q] = hi[(size_t)(a + q) * MM];
    }
    float out0 = 0.f, out1 = 0.f;
    #pragma unroll
    for (int q = 0; q < 4; ++q) {
        out0 += l[q] * DEC_LO[2 * q + 1] + h4[q] * DEC_HI[2 * q + 1];  // h = 2a
        out1 += l[q] * DEC_LO[2 * q]     + h4[q] * DEC_HI[2 * q];      // h = 2a+1
    }
    size_t base = ((size_t)(bc * 2 + fw) * HH + 2 * a) * MM + wo;
    u1[base]      = out0;
    u1[base + MM] = out1;
}

// ---------------- synthesis along W: u1 -> out (B,C,128,128) ----------------
__global__ __launch_bounds__(256) void idwt_w(const float* __restrict__ u1, float* __restrict__ out) {
    int idx = blockIdx.x * 256 + threadIdx.x;
    const int N = BB * CC * HH * (WW / 2);
    if (idx >= N) return;
    int a  = idx % (WW / 2);
    int h  = (idx / (WW / 2)) % HH;
    int bc = idx / ((WW / 2) * HH);
    const float* lo = u1 + (size_t)(bc * 2) * HH * MM + (size_t)h * MM;
    const float* hi = lo + (size_t)HH * MM;
    float l[4], h4[4];
    #pragma unroll
    for (int q = 0; q < 4; ++q) {
        l[q]  = lo[a + q];
        h4[q] = hi[a + q];
    }
    float out0 = 0.f, out1 = 0.f;
    #pragma unroll
    for (int q = 0; q < 4; ++q) {
        out0 += l[q] * DEC_LO[2 * q + 1] + h4[q] * DEC_HI[2 * q + 1];  // n = 2a
        out1 += l[q] * DEC_LO[2 * q]     + h4[q] * DEC_HI[2 * q];      // n = 2a+1
    }
    float2 r = make_float2(out0, out1);
    *(float2*)&out[((size_t)bc * HH + h) * WW + 2 * a] = r;
}

extern "C" void kernel_launch(void* const* d_in, const int* in_sizes, int n_in,
                              void* d_out, int out_size, void* d_ws, size_t ws_size,
                              hipStream_t stream) {
    const float* x  = (const float*)d_in[0];
    const float* w1 = (const float*)d_in[1];
    const float* w2 = (const float*)d_in[2];
    const float* w3 = (const float*)d_in[3];
    const float* w4 = (const float*)d_in[4];
    float* out = (float*)d_out;

    const size_t COEFF_FLTS = (size_t)BB * CC * 4 * MODES;
    float* buf1 = (float*)d_ws;
    float* buf2 = buf1 + COEFF_FLTS;

    // 1) DWT along W: x -> buf1 (t1)
    {
        dim3 grid(BB * CC, HH / 8);
        dwt_w<<<grid, 256, 0, stream>>>(x, buf1);
    }
    // 2) DWT along H: buf1 -> buf2 (coeff)
    {
        int N = BB * CC * 2 * ((MM + 1) / 2) * MM;
        dwt_h<<<(N + 255) / 256, 256, 0, stream>>>(buf1, buf2);
    }
    // 3) per-mode channel mixing: buf2 -> buf1 (mixed)
    {
        mix_k<<<2272, 256, 0, stream>>>(buf2, w1, w2, w3, w4, buf1);
    }
    // 4) inverse DWT along H: buf1 -> buf2 (u1)
    {
        int N = BB * CC * 2 * (HH / 2) * MM;
        idwt_h<<<(N + 255) / 256, 256, 0, stream>>>(buf1, buf2);
    }
    // 5) inverse DWT along W: buf2 -> d_out
    {
        int N = BB * CC * HH * (WW / 2);
        idwt_w<<<(N + 255) / 256, 256, 0, stream>>>(buf2, out);
    }
}

// Round 13
// 233.051 us; speedup vs baseline: 1.4706x; 1.4706x over previous
//
#include <hip/hip_runtime.h>

#define BB 16      // batch
#define CC 64      // channels (Cin = Cout = 64)
#define HH 128
#define WW 128
#define MM 67      // modes per axis
#define MODES (MM*MM)   // 4489
#define MC 32      // mode chunk for mix
#define NCHUNK 141 // ceil(4489/32)

typedef float f4 __attribute__((ext_vector_type(4)));

__constant__ float DEC_LO[8] = {-0.010597401784997278f, 0.032883011666982945f, 0.030841381835986965f,
                                -0.18703481171888114f, -0.02798376941698385f, 0.6308807679295904f,
                                0.7148465705525415f, 0.23037781330885523f};
__constant__ float DEC_HI[8] = {-0.23037781330885523f, 0.7148465705525415f, -0.6308807679295904f,
                                -0.02798376941698385f, 0.18703481171888114f, 0.030841381835986965f,
                                -0.032883011666982945f, -0.010597401784997278f};

// ---------------- fused DWT: x (B,C,H,W) -> cf (B,C,4,67,67) ----------------
// Block = one (b,c) image. t1 intermediate lives in LDS (68.6 KB, 2 blocks/CU)
// => the 70 MB t1 HBM round-trip of the unfused pair disappears.
__global__ __launch_bounds__(256, 2) void dwt_f(const float* __restrict__ x, float* __restrict__ cf) {
    __shared__ float st[2][HH][MM];   // t1 [f][h][wo]  68,608 B
    const int bc  = blockIdx.x;
    const int tid = threadIdx.x;
    const float* xr = x + (size_t)bc * HH * WW;

    // Phase A: W-transform. pair p = h*67+wo; 8 x-reads -> lo/hi.
    for (int p = tid; p < HH * MM; p += 256) {
        int wo = p % MM, h = p / MM;
        const float* row = xr + h * WW;
        float lo = 0.f, hi = 0.f;
        int base = 2 * wo - 6;
        #pragma unroll
        for (int k = 0; k < 8; ++k) {
            int i = base + k;
            i = (i < 0) ? (-i - 1) : i;
            i = (i >= WW) ? (2 * WW - 1 - i) : i;
            float v = row[i];
            lo += v * DEC_LO[7 - k];
            hi += v * DEC_HI[7 - k];
        }
        st[0][h][wo] = lo;
        st[1][h][wo] = hi;
    }
    __syncthreads();

    // Phase B: H-transform from LDS. q = hp*67+wo; both fw; 2 ho each.
    const int NH2 = (MM + 1) / 2;   // 34
    float* cfo = cf + (size_t)bc * 4 * MODES;
    for (int q = tid; q < NH2 * MM; q += 256) {
        int wo = q % MM, hp = q / MM;
        int ho0 = 2 * hp, ho1 = 2 * hp + 1;
        #pragma unroll
        for (int fw = 0; fw < 2; ++fw) {
            float rv[10];
            #pragma unroll
            for (int k = 0; k < 10; ++k) {
                int i = 4 * hp - 6 + k;
                i = (i < 0) ? (-i - 1) : i;
                i = (i >= HH) ? (2 * HH - 1 - i) : i;
                rv[k] = st[fw][i][wo];
            }
            float lo0 = 0.f, hi0 = 0.f, lo1 = 0.f, hi1 = 0.f;
            #pragma unroll
            for (int k = 0; k < 8; ++k) {
                lo0 += rv[k]     * DEC_LO[7 - k];
                hi0 += rv[k]     * DEC_HI[7 - k];
                lo1 += rv[k + 2] * DEC_LO[7 - k];
                hi1 += rv[k + 2] * DEC_HI[7 - k];
            }
            float* b0 = cfo + (size_t)(fw * 2 + 0) * MODES;
            float* b1 = cfo + (size_t)(fw * 2 + 1) * MODES;
            b0[ho0 * MM + wo] = lo0;
            b1[ho0 * MM + wo] = hi0;
            if (ho1 < MM) {
                b0[ho1 * MM + wo] = lo1;
                b1[ho1 * MM + wo] = hi1;
            }
        }
    }
}

// ---------------- per-mode channel mix (round-6 version, 128 us, verbatim) ----
// out[b,o,band,m] = sum_i cf[b,i,band,m] * w_band[i,o,m]
__global__ __launch_bounds__(256) void mix_k(const float* __restrict__ cf,
                                             const float* __restrict__ w1,
                                             const float* __restrict__ w2,
                                             const float* __restrict__ w3,
                                             const float* __restrict__ w4,
                                             float* __restrict__ out) {
    __shared__ float sc[BB][CC][MC];   // [b][i][m] 128 KB
    // --- bijective XCD swizzle over NWG = 141*4 = 564 = 8*70 + 4 ---
    int flat = blockIdx.y * NCHUNK + blockIdx.x;
    {
        const int q = 564 / 8, r = 564 % 8;          // 70, 4
        int xcd = flat & 7, j = flat >> 3;
        flat = (xcd < r ? xcd * (q + 1) : r * (q + 1) + (xcd - r) * q) + j;
    }
    const int band = flat / NCHUNK;
    const int m0   = min((flat % NCHUNK) * MC, MODES - MC);
    const int tid  = threadIdx.x;
    const float* w = (band == 0) ? w1 : (band == 1) ? w2 : (band == 2) ? w3 : w4;

    // ---- stage coeff tile: 1024 rows (b*64+i) x 32 floats ----
    {
        const int c = tid & 7, r0 = tid >> 3;        // 8 threads/row
        #pragma unroll
        for (int p = 0; p < 32; ++p) {
            int r = r0 + (p << 5);                   // 0..1023
            f4 v = *(const f4*)(cf + ((size_t)(r * 4) + band) * MODES + m0 + c * 4);
            *(f4*)&sc[r >> 6][r & 63][c * 4] = v;
        }
    }
    __syncthreads();

    const int lane = tid & 63, wv = tid >> 6;
    const int o2 = wv * 8 + (lane >> 3);   // 0..31  (thread computes o2 and o2+32)
    const int mc4 = (lane & 7) * 4;        // mode sub-offset
    const size_t IST = (size_t)CC * MODES;
    const float* wpl = w + (size_t)o2 * MODES + m0 + mc4;
    const float* wph = wpl + (size_t)32 * MODES;

    f4 accL[16], accH[16];
    #pragma unroll
    for (int b = 0; b < 16; ++b) { accL[b] = (f4)(0.f); accH[b] = (f4)(0.f); }

    f4 al0, al1, al2, al3, ah0, ah1, ah2, ah3;
    f4 bl0, bl1, bl2, bl3, bh0, bh1, bh2, bh3;
    al0 = *(const f4*)(wpl + 0 * IST);  ah0 = *(const f4*)(wph + 0 * IST);
    al1 = *(const f4*)(wpl + 1 * IST);  ah1 = *(const f4*)(wph + 1 * IST);
    al2 = *(const f4*)(wpl + 2 * IST);  ah2 = *(const f4*)(wph + 2 * IST);
    al3 = *(const f4*)(wpl + 3 * IST);  ah3 = *(const f4*)(wph + 3 * IST);

    #pragma unroll 1
    for (int ib = 0; ib < 64; ib += 8) {
        bl0 = *(const f4*)(wpl + (size_t)(ib + 4) * IST);  bh0 = *(const f4*)(wph + (size_t)(ib + 4) * IST);
        bl1 = *(const f4*)(wpl + (size_t)(ib + 5) * IST);  bh1 = *(const f4*)(wph + (size_t)(ib + 5) * IST);
        bl2 = *(const f4*)(wpl + (size_t)(ib + 6) * IST);  bh2 = *(const f4*)(wph + (size_t)(ib + 6) * IST);
        bl3 = *(const f4*)(wpl + (size_t)(ib + 7) * IST);  bh3 = *(const f4*)(wph + (size_t)(ib + 7) * IST);
        #pragma unroll
        for (int b = 0; b < 16; ++b) {
            f4 s = *(const f4*)&sc[b][ib + 0][mc4];
            accL[b] += s * al0;  accH[b] += s * ah0;
        }
        #pragma unroll
        for (int b = 0; b < 16; ++b) {
            f4 s = *(const f4*)&sc[b][ib + 1][mc4];
            accL[b] += s * al1;  accH[b] += s * ah1;
        }
        #pragma unroll
        for (int b = 0; b < 16; ++b) {
            f4 s = *(const f4*)&sc[b][ib + 2][mc4];
            accL[b] += s * al2;  accH[b] += s * ah2;
        }
        #pragma unroll
        for (int b = 0; b < 16; ++b) {
            f4 s = *(const f4*)&sc[b][ib + 3][mc4];
            accL[b] += s * al3;  accH[b] += s * ah3;
        }
        if (ib + 8 < 64) {
            al0 = *(const f4*)(wpl + (size_t)(ib + 8)  * IST);  ah0 = *(const f4*)(wph + (size_t)(ib + 8)  * IST);
            al1 = *(const f4*)(wpl + (size_t)(ib + 9)  * IST);  ah1 = *(const f4*)(wph + (size_t)(ib + 9)  * IST);
            al2 = *(const f4*)(wpl + (size_t)(ib + 10) * IST);  ah2 = *(const f4*)(wph + (size_t)(ib + 10) * IST);
            al3 = *(const f4*)(wpl + (size_t)(ib + 11) * IST);  ah3 = *(const f4*)(wph + (size_t)(ib + 11) * IST);
        }
        #pragma unroll
        for (int b = 0; b < 16; ++b) {
            f4 s = *(const f4*)&sc[b][ib + 4][mc4];
            accL[b] += s * bl0;  accH[b] += s * bh0;
        }
        #pragma unroll
        for (int b = 0; b < 16; ++b) {
            f4 s = *(const f4*)&sc[b][ib + 5][mc4];
            accL[b] += s * bl1;  accH[b] += s * bh1;
        }
        #pragma unroll
        for (int b = 0; b < 16; ++b) {
            f4 s = *(const f4*)&sc[b][ib + 6][mc4];
            accL[b] += s * bl2;  accH[b] += s * bh2;
        }
        #pragma unroll
        for (int b = 0; b < 16; ++b) {
            f4 s = *(const f4*)&sc[b][ib + 7][mc4];
            accL[b] += s * bl3;  accH[b] += s * bh3;
        }
    }

    #pragma unroll
    for (int b = 0; b < 16; ++b) {
        *(f4*)&out[((size_t)((b * CC + o2) * 4) + band) * MODES + m0 + mc4] = accL[b];
        *(f4*)&out[((size_t)((b * CC + o2 + 32) * 4) + band) * MODES + m0 + mc4] = accH[b];
    }
}

// ---------------- fused IDWT: mixed (B,C,4,67,67) -> out (B,C,128,128) -------
// Block = one (b,c). u1 intermediate in LDS (68.6 KB, 2 blocks/CU) => the
// 70 MB u1 HBM round-trip disappears.
__global__ __launch_bounds__(256, 2) void idwt_f(const float* __restrict__ mx, float* __restrict__ out) {
    __shared__ float su[2][HH][MM];   // u1 [fw][h][wo]  68,608 B
    const int bc  = blockIdx.x;
    const int tid = threadIdx.x;
    const float* mxb = mx + (size_t)bc * 4 * MODES;

    // Phase A: H-synthesis (polyphase pair h=2a,2a+1). p = (fw*64+a)*67+wo.
    for (int p = tid; p < 2 * (HH / 2) * MM; p += 256) {
        int wo = p % MM;
        int a  = (p / MM) % (HH / 2);
        int fw = p / (MM * (HH / 2));
        const float* lo = mxb + (size_t)(fw * 2) * MODES + wo;
        const float* hi = lo + MODES;
        float l[4], h4[4];
        #pragma unroll
        for (int q = 0; q < 4; ++q) {
            l[q]  = lo[(a + q) * MM];
            h4[q] = hi[(a + q) * MM];
        }
        float o0 = 0.f, o1 = 0.f;
        #pragma unroll
        for (int q = 0; q < 4; ++q) {
            o0 += l[q] * DEC_LO[2 * q + 1] + h4[q] * DEC_HI[2 * q + 1];  // h = 2a
            o1 += l[q] * DEC_LO[2 * q]     + h4[q] * DEC_HI[2 * q];      // h = 2a+1
        }
        su[fw][2 * a][wo]     = o0;
        su[fw][2 * a + 1][wo] = o1;
    }
    __syncthreads();

    // Phase B: W-synthesis from LDS. p = h*64+a; float2 store.
    float* ob = out + (size_t)bc * HH * WW;
    for (int p = tid; p < HH * (WW / 2); p += 256) {
        int a = p & 63, h = p >> 6;
        float l[4], h4[4];
        #pragma unroll
        for (int q = 0; q < 4; ++q) {
            l[q]  = su[0][h][a + q];
            h4[q] = su[1][h][a + q];
        }
        float o0 = 0.f, o1 = 0.f;
        #pragma unroll
        for (int q = 0; q < 4; ++q) {
            o0 += l[q] * DEC_LO[2 * q + 1] + h4[q] * DEC_HI[2 * q + 1];  // n = 2a
            o1 += l[q] * DEC_LO[2 * q]     + h4[q] * DEC_HI[2 * q];      // n = 2a+1
        }
        *(float2*)&ob[h * WW + 2 * a] = make_float2(o0, o1);
    }
}

extern "C" void kernel_launch(void* const* d_in, const int* in_sizes, int n_in,
                              void* d_out, int out_size, void* d_ws, size_t ws_size,
                              hipStream_t stream) {
    const float* x  = (const float*)d_in[0];
    const float* w1 = (const float*)d_in[1];
    const float* w2 = (const float*)d_in[2];
    const float* w3 = (const float*)d_in[3];
    const float* w4 = (const float*)d_in[4];
    float* out = (float*)d_out;

    const size_t COEFF_FLTS = (size_t)BB * CC * 4 * MODES;
    float* buf1 = (float*)d_ws;            // coeff
    float* buf2 = buf1 + COEFF_FLTS;       // mixed

    // 1) fused DWT: x -> buf1 (coeff)
    dwt_f<<<BB * CC, 256, 0, stream>>>(x, buf1);
    // 2) per-mode channel mixing: buf1 -> buf2 (mixed)
    {
        dim3 grid(NCHUNK, 4);   // (141 mode-chunks, 4 bands)
        mix_k<<<grid, 256, 0, stream>>>(buf1, w1, w2, w3, w4, buf2);
    }
    // 3) fused IDWT: buf2 -> d_out
    idwt_f<<<BB * CC, 256, 0, stream>>>(buf2, out);
}